// Round 1
// baseline (505.930 us; speedup 1.0000x reference)
//
#include <hip/hip_runtime.h>
#include <math.h>

// Problem constants (from reference)
#define NSP    4
#define NMAX   8
#define LSH    7
#define NTOT   (NSP * NMAX)          // 32
#define ROWLEN (NTOT * LSH * LSH)    // 1568 floats per j
#define NPAIR  ((NTOT * (NTOT + 1)) / 2)   // 528 upper-tri pairs
#define NPAIR_PADDED (((NTOT + 1) * (NTOT + 1)) / 2) // 544
#define NVALS  (NPAIR * LSH)         // 3696 real values
#define OUTLEN (NPAIR_PADDED * LSH)  // 3808 output floats per j
#define EPSF   1e-12f

__global__ __launch_bounds__(256) void powerspectrum_kernel(
    const float* __restrict__ se, float* __restrict__ out)
{
    const int j   = blockIdx.x;
    const int tid = threadIdx.x;

    __shared__ float s_in[ROWLEN];        // 6272 B
    __shared__ float s_out[OUTLEN];       // 15232 B
    __shared__ float s_red[4];
    __shared__ unsigned char s_p[NPAIR], s_q[NPAIR];

    // ---- stage input row (coalesced float4) ----
    const float4* row4 = reinterpret_cast<const float4*>(se + (size_t)j * ROWLEN);
    float4* s_in4 = reinterpret_cast<float4*>(s_in);
    #pragma unroll
    for (int i = tid; i < ROWLEN / 4; i += 256) s_in4[i] = row4[i];

    // ---- build upper-triangle pair table (p<=q), pair index = p*N - p(p-1)/2 + (q-p) ----
    if (tid < NTOT) {
        const int p = tid;
        const int base = p * NTOT - (p * (p - 1)) / 2;
        for (int q = p; q < NTOT; ++q) {
            s_p[base + q - p] = (unsigned char)p;
            s_q[base + q - p] = (unsigned char)q;
        }
    }

    // ---- zero the pad region (indices NVALS..OUTLEN-1) ----
    for (int i = NVALS + tid; i < OUTLEN; i += 256) s_out[i] = 0.0f;

    __syncthreads();

    // ---- compute values + partial sum of squares ----
    const float SQRT2 = 1.41421356237309514547f;
    float ss = 0.0f;
    for (int c = tid; c < NVALS; c += 256) {
        const int pair = c / LSH;
        const int l    = c - pair * LSH;
        const int p    = s_p[pair];
        const int q    = s_q[pair];
        const int off  = l * l;          // cumulative (2i+1) = l^2
        const int lbs  = 2 * l + 1;
        const float* ap = s_in + p * (LSH * LSH) + off;
        const float* bq = s_in + q * (LSH * LSH) + off;
        float dot = 0.0f;
        for (int m = 0; m < lbs; ++m) dot += ap[m] * bq[m];
        float val = dot * (1.0f / sqrtf((float)lbs));
        if (p != q) val *= SQRT2;
        s_out[c] = val;
        ss += val * val;
    }

    // ---- block reduction of ss (4 waves of 64) ----
    #pragma unroll
    for (int o = 32; o > 0; o >>= 1) ss += __shfl_down(ss, o, 64);
    if ((tid & 63) == 0) s_red[tid >> 6] = ss;
    __syncthreads();
    const float total = s_red[0] + s_red[1] + s_red[2] + s_red[3];
    const float inv = 1.0f / fmaxf(sqrtf(total), EPSF);

    // ---- normalized coalesced write (float4: 3808/4 = 952 per row) ----
    float4* o4 = reinterpret_cast<float4*>(out + (size_t)j * OUTLEN);
    const float4* s_out4 = reinterpret_cast<const float4*>(s_out);
    for (int i = tid; i < OUTLEN / 4; i += 256) {
        float4 v = s_out4[i];
        v.x *= inv; v.y *= inv; v.z *= inv; v.w *= inv;
        o4[i] = v;
    }
}

extern "C" void kernel_launch(void* const* d_in, const int* in_sizes, int n_in,
                              void* d_out, int out_size, void* d_ws, size_t ws_size,
                              hipStream_t stream) {
    const float* se = (const float*)d_in[0];
    float* out = (float*)d_out;
    const int j = in_sizes[0] / ROWLEN;   // 20000
    powerspectrum_kernel<<<j, 256, 0, stream>>>(se, out);
}

// Round 3
// 406.164 us; speedup vs baseline: 1.2456x; 1.2456x over previous
//
#include <hip/hip_runtime.h>
#include <math.h>

// Problem constants (from reference)
#define NSP    4
#define NMAX   8
#define LSH    7
#define NTOT   (NSP * NMAX)          // 32
#define ROWLEN (NTOT * LSH * LSH)    // 1568 floats per j
#define RPAD   52                    // padded row stride (52*4=208 B, 16B-aligned)
#define NPAIR  ((NTOT * (NTOT + 1)) / 2)   // 528
#define NPAIR_PADDED (((NTOT + 1) * (NTOT + 1)) / 2) // 544
#define NVALS  (NPAIR * LSH)         // 3696
#define OUTLEN (NPAIR_PADDED * LSH)  // 3808
#define EPSF   1e-12f

__global__ __launch_bounds__(256) void powerspectrum_kernel(
    const float* __restrict__ se, float* __restrict__ out)
{
    const int j   = blockIdx.x;
    const int tid = threadIdx.x;

    __shared__ float s_in[NTOT * RPAD];   // 6656 B, rows padded 49->52
    __shared__ float s_out[OUTLEN];       // 15232 B
    __shared__ float s_red[4];
    __shared__ unsigned char s_p[NPAIR], s_q[NPAIR];

    // ---- stage input row: coalesced float4 read, scalar scatter to padded rows ----
    const float4* row4 = reinterpret_cast<const float4*>(se + (size_t)j * ROWLEN);
    #pragma unroll
    for (int i = tid; i < ROWLEN / 4; i += 256) {
        float4 v = row4[i];
        int f = 4 * i;
        int a0 = f / 49,      m0 = f - 49 * a0;       s_in[a0 * RPAD + m0] = v.x;
        int f1 = f + 1; int a1 = f1 / 49, m1 = f1 - 49 * a1; s_in[a1 * RPAD + m1] = v.y;
        int f2 = f + 2; int a2 = f2 / 49, m2 = f2 - 49 * a2; s_in[a2 * RPAD + m2] = v.z;
        int f3 = f + 3; int a3 = f3 / 49, m3 = f3 - 49 * a3; s_in[a3 * RPAD + m3] = v.w;
    }

    // ---- pair tables ----
    if (tid < NTOT) {
        const int p = tid;
        const int base = p * NTOT - (p * (p - 1)) / 2;
        for (int q = p; q < NTOT; ++q) {
            s_p[base + q - p] = (unsigned char)p;
            s_q[base + q - p] = (unsigned char)q;
        }
    }

    // ---- zero pad region ----
    for (int i = NVALS + tid; i < OUTLEN; i += 256) s_out[i] = 0.0f;

    __syncthreads();

    const float SQRT2 = 1.41421356237309504880f;
    const float sc1 = 0.57735026918962576451f;   // 1/sqrt(3)
    const float sc2 = 0.44721359549995793928f;   // 1/sqrt(5)
    const float sc3 = 0.37796447300922722721f;   // 1/sqrt(7)
    const float sc4 = 0.33333333333333333333f;   // 1/3
    const float sc5 = 0.30151134457776362265f;   // 1/sqrt(11)
    const float sc6 = 0.27735009811261456101f;   // 1/sqrt(13)

    float ss = 0.0f;
    for (int pair = tid; pair < NPAIR; pair += 256) {
        const int p = s_p[pair], q = s_q[pair];
        const float4* a4 = reinterpret_cast<const float4*>(s_in + p * RPAD);
        const float4* b4 = reinterpret_cast<const float4*>(s_in + q * RPAD);
        float d0, d1, d2, d3, d4, d5, d6;
        float4 av, bv;
        // m = 0..48, l-blocks at offsets l^2 with length 2l+1; fully unrolled
        av = a4[0];  bv = b4[0];
        d0 = av.x * bv.x;
        d1 = av.y * bv.y; d1 = fmaf(av.z, bv.z, d1); d1 = fmaf(av.w, bv.w, d1);
        av = a4[1];  bv = b4[1];
        d2 = av.x * bv.x; d2 = fmaf(av.y, bv.y, d2); d2 = fmaf(av.z, bv.z, d2); d2 = fmaf(av.w, bv.w, d2);
        av = a4[2];  bv = b4[2];
        d2 = fmaf(av.x, bv.x, d2);
        d3 = av.y * bv.y; d3 = fmaf(av.z, bv.z, d3); d3 = fmaf(av.w, bv.w, d3);
        av = a4[3];  bv = b4[3];
        d3 = fmaf(av.x, bv.x, d3); d3 = fmaf(av.y, bv.y, d3); d3 = fmaf(av.z, bv.z, d3); d3 = fmaf(av.w, bv.w, d3);
        av = a4[4];  bv = b4[4];
        d4 = av.x * bv.x; d4 = fmaf(av.y, bv.y, d4); d4 = fmaf(av.z, bv.z, d4); d4 = fmaf(av.w, bv.w, d4);
        av = a4[5];  bv = b4[5];
        d4 = fmaf(av.x, bv.x, d4); d4 = fmaf(av.y, bv.y, d4); d4 = fmaf(av.z, bv.z, d4); d4 = fmaf(av.w, bv.w, d4);
        av = a4[6];  bv = b4[6];
        d4 = fmaf(av.x, bv.x, d4);
        d5 = av.y * bv.y; d5 = fmaf(av.z, bv.z, d5); d5 = fmaf(av.w, bv.w, d5);
        av = a4[7];  bv = b4[7];
        d5 = fmaf(av.x, bv.x, d5); d5 = fmaf(av.y, bv.y, d5); d5 = fmaf(av.z, bv.z, d5); d5 = fmaf(av.w, bv.w, d5);
        av = a4[8];  bv = b4[8];
        d5 = fmaf(av.x, bv.x, d5); d5 = fmaf(av.y, bv.y, d5); d5 = fmaf(av.z, bv.z, d5); d5 = fmaf(av.w, bv.w, d5);
        av = a4[9];  bv = b4[9];
        d6 = av.x * bv.x; d6 = fmaf(av.y, bv.y, d6); d6 = fmaf(av.z, bv.z, d6); d6 = fmaf(av.w, bv.w, d6);
        av = a4[10]; bv = b4[10];
        d6 = fmaf(av.x, bv.x, d6); d6 = fmaf(av.y, bv.y, d6); d6 = fmaf(av.z, bv.z, d6); d6 = fmaf(av.w, bv.w, d6);
        av = a4[11]; bv = b4[11];
        d6 = fmaf(av.x, bv.x, d6); d6 = fmaf(av.y, bv.y, d6); d6 = fmaf(av.z, bv.z, d6); d6 = fmaf(av.w, bv.w, d6);
        av = a4[12]; bv = b4[12];
        d6 = fmaf(av.x, bv.x, d6);   // m=48; m=49..51 are padding, skipped

        const float f = (p == q) ? 1.0f : SQRT2;
        const float v0 = d0 * f;
        const float v1 = d1 * (sc1 * f);
        const float v2 = d2 * (sc2 * f);
        const float v3 = d3 * (sc3 * f);
        const float v4 = d4 * (sc4 * f);
        const float v5 = d5 * (sc5 * f);
        const float v6 = d6 * (sc6 * f);
        float* o = s_out + pair * LSH;
        o[0] = v0; o[1] = v1; o[2] = v2; o[3] = v3; o[4] = v4; o[5] = v5; o[6] = v6;
        ss += v0 * v0 + v1 * v1 + v2 * v2 + v3 * v3 + v4 * v4 + v5 * v5 + v6 * v6;
    }

    // ---- block reduction of ss ----
    #pragma unroll
    for (int o = 32; o > 0; o >>= 1) ss += __shfl_down(ss, o, 64);
    if ((tid & 63) == 0) s_red[tid >> 6] = ss;
    __syncthreads();
    const float total = s_red[0] + s_red[1] + s_red[2] + s_red[3];
    const float inv = 1.0f / fmaxf(sqrtf(total), EPSF);

    // ---- normalized coalesced write ----
    float4* o4 = reinterpret_cast<float4*>(out + (size_t)j * OUTLEN);
    const float4* so4 = reinterpret_cast<const float4*>(s_out);
    #pragma unroll
    for (int i = tid; i < OUTLEN / 4; i += 256) {
        float4 v = so4[i];
        v.x *= inv; v.y *= inv; v.z *= inv; v.w *= inv;
        o4[i] = v;
    }
}

extern "C" void kernel_launch(void* const* d_in, const int* in_sizes, int n_in,
                              void* d_out, int out_size, void* d_ws, size_t ws_size,
                              hipStream_t stream) {
    const float* se = (const float*)d_in[0];
    float* out = (float*)d_out;
    const int j = in_sizes[0] / ROWLEN;   // 20000
    powerspectrum_kernel<<<j, 256, 0, stream>>>(se, out);
}